// Round 1
// baseline (738.509 us; speedup 1.0000x reference)
//
#include <hip/hip_runtime.h>

// SingleGcnLayer: y = relu( ((targets ⊕ Σ_k neighbors) @ kernel) / max-guard(Σ a) )
// Shapes: targets[32,1024,256] f32, neighbors[32,1024,16,256] f32,
//         a[32,1024,17] f32, kernel[256,256] f32  ->  out[32,1024,256] f32.
// Memory-bound: 605 MB min traffic -> ~96 us floor at 6.3 TB/s.

typedef float v4f __attribute__((ext_vector_type(4)));

#define BB 32
#define NN 1024
#define KK 16
#define DD 256
#define LL 256
#define ROWS 32      // rows (b,n) per block
#define DTILE 16     // kernel-matrix d rows staged per pass (16 KB LDS)
#define NTHREADS 256

__global__ __launch_bounds__(NTHREADS, 3)
void gcn_fused(const float* __restrict__ targets,
               const float* __restrict__ neighbors,
               const float* __restrict__ a,
               const float* __restrict__ kern,
               float* __restrict__ out) {
    __shared__ float s[ROWS * DD];     // 32 KB: reduced neighborhood rows
    __shared__ float kt[DTILE * LL];   // 16 KB: kernel d-tile
    __shared__ float invf[ROWS];

    const int t        = threadIdx.x;
    const int w        = t >> 6;       // wave 0..3
    const int lane     = t & 63;
    const int row_base = blockIdx.x * ROWS;

    // ---- degree factor: one thread per row (tiny, L1-served) ----
    if (t < ROWS) {
        const float* ap = a + (row_base + t) * (KK + 1);
        float f = 0.0f;
        #pragma unroll
        for (int j = 0; j < KK + 1; ++j) f += ap[j];
        invf[t] = (f > 0.5f) ? (1.0f / f) : 1.0f;
    }

    // ---- phase 1: s[r][d] = targets[row][d] + sum_k neighbors[row][k][d] ----
    // wave w owns rows w*8 .. w*8+7; lane covers d = 4*lane..4*lane+3.
    // 17 independent float4 nontemporal loads per row per lane (streamed once).
    const v4f* t4 = (const v4f*)targets;
    const v4f* n4 = (const v4f*)neighbors;
    #pragma unroll
    for (int r = 0; r < 8; ++r) {
        const int rl   = w * 8 + r;
        const int grow = row_base + rl;
        v4f accum = __builtin_nontemporal_load(&t4[grow * (DD / 4) + lane]);
        #pragma unroll
        for (int k = 0; k < KK; ++k) {
            accum += __builtin_nontemporal_load(&n4[(grow * KK + k) * (DD / 4) + lane]);
        }
        *(v4f*)&s[rl * DD + lane * 4] = accum;   // ds_write_b128, lane-contiguous
    }

    v4f acc[8];
    #pragma unroll
    for (int r = 0; r < 8; ++r) acc[r] = v4f{0.0f, 0.0f, 0.0f, 0.0f};

    // ---- phase 2: acc[r][j] += s[r][d] * kernel[d][j], d-tiled through LDS ----
    const v4f* k4 = (const v4f*)kern;
    for (int dt = 0; dt < DD / DTILE; ++dt) {      // 16 passes
        __syncthreads();                           // protect kt from prior readers
        #pragma unroll
        for (int i = 0; i < (DTILE * LL / 4) / NTHREADS; ++i) {   // 4 float4/thread
            v4f v = k4[dt * (DTILE * LL / 4) + i * NTHREADS + t]; // coalesced, L2-hot
            *(v4f*)&kt[(i * NTHREADS + t) * 4] = v;
        }
        __syncthreads();
        #pragma unroll
        for (int dd = 0; dd < DTILE / 4; ++dd) {   // 4 d-values per iter
            const int d0 = dt * DTILE + dd * 4;
            // kernel rows: lane-contiguous b128, conflict-free
            v4f kv0 = *(const v4f*)&kt[(dd * 4 + 0) * LL + lane * 4];
            v4f kv1 = *(const v4f*)&kt[(dd * 4 + 1) * LL + lane * 4];
            v4f kv2 = *(const v4f*)&kt[(dd * 4 + 2) * LL + lane * 4];
            v4f kv3 = *(const v4f*)&kt[(dd * 4 + 3) * LL + lane * 4];
            #pragma unroll
            for (int r = 0; r < 8; ++r) {
                // wave-uniform address -> LDS broadcast, free
                v4f sv = *(const v4f*)&s[(w * 8 + r) * DD + d0];
                acc[r] += sv.x * kv0;
                acc[r] += sv.y * kv1;
                acc[r] += sv.z * kv2;
                acc[r] += sv.w * kv3;
            }
        }
    }

    // ---- epilogue: normalize, relu, coalesced nontemporal store ----
    #pragma unroll
    for (int r = 0; r < 8; ++r) {
        const int rl  = w * 8 + r;
        const float inv = invf[rl];
        v4f v = acc[r] * inv;
        v.x = fmaxf(v.x, 0.0f);
        v.y = fmaxf(v.y, 0.0f);
        v.z = fmaxf(v.z, 0.0f);
        v.w = fmaxf(v.w, 0.0f);
        __builtin_nontemporal_store(v, (v4f*)&out[(row_base + rl) * LL + lane * 4]);
    }
}

extern "C" void kernel_launch(void* const* d_in, const int* in_sizes, int n_in,
                              void* d_out, int out_size, void* d_ws, size_t ws_size,
                              hipStream_t stream) {
    const float* targets   = (const float*)d_in[0];
    const float* neighbors = (const float*)d_in[1];
    const float* a         = (const float*)d_in[2];
    const float* kern      = (const float*)d_in[3];
    float* out = (float*)d_out;
    const int blocks = (BB * NN) / ROWS;   // 1024
    gcn_fused<<<dim3(blocks), dim3(NTHREADS), 0, stream>>>(targets, neighbors, a, kern, out);
}

// Round 2
// 730.686 us; speedup vs baseline: 1.0107x; 1.0107x over previous
//
#include <hip/hip_runtime.h>

// SingleGcnLayer: y = relu( ((targets ⊕ Σ_k neighbors) @ kernel) / guard(Σ a) )
// targets[32,1024,256] f32, neighbors[32,1024,16,256] f32, a[32,1024,17] f32,
// kernel[256,256] f32 -> out[32,1024,256] f32.
// Round 2: s stays in registers (no LDS round-trip); broadcast s[r][d] via
// v_readlane -> SGPR -> v_fmac. LDS holds only double-buffered 16KB kernel
// tiles. One barrier/pass. DS-pipe time 61us -> ~20us; 16 waves/CU.

typedef float v4f __attribute__((ext_vector_type(4)));

#define BB 32
#define NN 1024
#define KK 16
#define DD 256
#define LL 256
#define ROWS 32      // rows (b,n) per block; 8 per wave
#define DTILE 16     // kernel d-rows per pass
#define NPASS (DD / DTILE)
#define NTHREADS 256

__device__ __forceinline__ float bcast_lane(float x, int lane) {
    return __int_as_float(__builtin_amdgcn_readlane(__float_as_int(x), lane));
}

__global__ __launch_bounds__(NTHREADS, 4)
void gcn_fused(const float* __restrict__ targets,
               const float* __restrict__ neighbors,
               const float* __restrict__ a,
               const float* __restrict__ kern,
               float* __restrict__ out) {
    __shared__ float kt[2][DTILE * LL];   // 2 x 16 KB kernel tiles
    __shared__ float invf[ROWS];

    const int t        = threadIdx.x;
    const int w        = t >> 6;          // wave 0..3
    const int lane     = t & 63;
    const int row_base = blockIdx.x * ROWS;

    const v4f* k4 = (const v4f*)kern;

    // ---- issue tile-0 kernel stage loads first (L2-resident after block 0) ----
    v4f stage[4];
    #pragma unroll
    for (int i = 0; i < 4; ++i) stage[i] = k4[i * NTHREADS + t];

    // ---- degree factor (tiny) ----
    if (t < ROWS) {
        const float* ap = a + (size_t)(row_base + t) * (KK + 1);
        float f = 0.0f;
        #pragma unroll
        for (int j = 0; j < KK + 1; ++j) f += ap[j];
        invf[t] = (f > 0.5f) ? (1.0f / f) : 1.0f;
    }

    // ---- phase 1: sreg[r] = targets[row] + sum_k neighbors[row][k], in regs ----
    // wave w owns rows w*8..w*8+7; lane holds d = 4*lane..4*lane+3.
    const v4f* t4 = (const v4f*)targets;
    const v4f* n4 = (const v4f*)neighbors;
    v4f sreg[8];
    #pragma unroll
    for (int r = 0; r < 8; ++r) {
        const int grow = row_base + w * 8 + r;
        v4f accum = __builtin_nontemporal_load(&t4[(size_t)grow * (DD / 4) + lane]);
        #pragma unroll 4
        for (int k = 0; k < KK; ++k) {
            accum += __builtin_nontemporal_load(
                &n4[((size_t)grow * KK + k) * (DD / 4) + lane]);
        }
        sreg[r] = accum;
    }

    // ---- write tile 0, converge ----
    #pragma unroll
    for (int i = 0; i < 4; ++i)
        *(v4f*)&kt[0][(i * NTHREADS + t) * 4] = stage[i];
    __syncthreads();

    v4f acc[8];
    #pragma unroll
    for (int r = 0; r < 8; ++r) acc[r] = v4f{0.0f, 0.0f, 0.0f, 0.0f};

    // ---- phase 2: acc[r][cols 4*lane..+3] += s[r][d] * K[d][cols] ----
    for (int dt = 0; dt < NPASS; ++dt) {
        const int cur = dt & 1;
        if (dt < NPASS - 1) {   // prefetch next tile (consumed ~1 pass later)
            #pragma unroll
            for (int i = 0; i < 4; ++i)
                stage[i] = k4[(dt + 1) * (DTILE * LL / 4) + i * NTHREADS + t];
        }
        #pragma unroll
        for (int dd = 0; dd < DTILE; ++dd) {
            // K row d, this lane's 4 columns: lane-contiguous b128, conflict-free
            v4f kv = *(const v4f*)&kt[cur][dd * LL + 4 * lane];
            const int chunk = dt * (DTILE / 4) + (dd >> 2);  // wave-uniform lane idx
            #pragma unroll
            for (int r = 0; r < 8; ++r) {
                const float sv = bcast_lane(sreg[r][dd & 3], chunk); // s[r][d] -> SGPR
                acc[r] += sv * kv;   // v_fmac_f32 with SGPR operand
            }
        }
        if (dt < NPASS - 1) {
            *(v4f*)&kt[cur ^ 1][(0 * NTHREADS + t) * 4] = stage[0];
            *(v4f*)&kt[cur ^ 1][(1 * NTHREADS + t) * 4] = stage[1];
            *(v4f*)&kt[cur ^ 1][(2 * NTHREADS + t) * 4] = stage[2];
            *(v4f*)&kt[cur ^ 1][(3 * NTHREADS + t) * 4] = stage[3];
            __syncthreads();   // one barrier per pass
        }
    }

    // ---- epilogue: normalize, relu, coalesced nontemporal store ----
    #pragma unroll
    for (int r = 0; r < 8; ++r) {
        const int rl    = w * 8 + r;
        const float inv = invf[rl];
        v4f v = acc[r] * inv;
        v.x = fmaxf(v.x, 0.0f);
        v.y = fmaxf(v.y, 0.0f);
        v.z = fmaxf(v.z, 0.0f);
        v.w = fmaxf(v.w, 0.0f);
        __builtin_nontemporal_store(v, (v4f*)&out[(size_t)(row_base + rl) * LL + 4 * lane]);
    }
}

extern "C" void kernel_launch(void* const* d_in, const int* in_sizes, int n_in,
                              void* d_out, int out_size, void* d_ws, size_t ws_size,
                              hipStream_t stream) {
    const float* targets   = (const float*)d_in[0];
    const float* neighbors = (const float*)d_in[1];
    const float* a         = (const float*)d_in[2];
    const float* kern      = (const float*)d_in[3];
    float* out = (float*)d_out;
    const int blocks = (BB * NN) / ROWS;   // 1024
    gcn_fused<<<dim3(blocks), dim3(NTHREADS), 0, stream>>>(targets, neighbors, a, kern, out);
}